// Round 5
// baseline (522.279 us; speedup 1.0000x reference)
//
#include <hip/hip_runtime.h>

#define TPB 256
#define BEB 2048  // edges per bucket block (LDS-staged)
#define SEB 2048  // edges per scatter2 block

// ---------- index-width adaptive loads ----------
__global__ void k_detect_i64(const unsigned int* __restrict__ ei, int E,
                             int* __restrict__ flag) {
  __shared__ int nz;
  if (threadIdx.x == 0) nz = 0;
  __syncthreads();
  int step = E / 4096;
  if (step < 1) step = 1;
  for (int t = threadIdx.x; t < 4096; t += blockDim.x) {
    long long pos = 1 + 2LL * (long long)t * step;   // odd dword positions
    if (pos < 2LL * (long long)E && ei[pos] != 0u) atomicAdd(&nz, 1);
  }
  __syncthreads();
  if (threadIdx.x == 0) *flag = (nz == 0) ? 1 : 0;
}

__device__ __forceinline__ int load_idx(const void* __restrict__ p, long long pos,
                                        int is64) {
  if (is64) return (int)(((const long long*)p)[pos]);
  return ((const int*)p)[pos];
}

// ---------- zero degi (N) and ccnt (8) ----------
__global__ void k_zero(int* __restrict__ degi, int* __restrict__ ccnt, int n) {
  int i = blockIdx.x * blockDim.x + threadIdx.x;
  if (i < n) degi[i] = 0;
  if (i < 8) ccnt[i] = 0;
}

// ---------- degree hist + per-chunk edge counts ----------
__global__ void k_count(const void* __restrict__ ei, const int* __restrict__ flag,
                        int* __restrict__ degi, int* __restrict__ ccnt,
                        int E, float invNc) {
  __shared__ int bins[8];
  if (threadIdx.x < 8) bins[threadIdx.x] = 0;
  __syncthreads();
  int e = blockIdx.x * blockDim.x + threadIdx.x;
  if (e < E) {
    int is64 = *flag;
    int d = load_idx(ei, (long long)E + e, is64);
    atomicAdd(&degi[d], 1);
    int g = min(7, (int)((float)d * invNc));
    atomicAdd(&bins[g], 1);
  }
  __syncthreads();
  if (threadIdx.x < 8 && bins[threadIdx.x] > 0)
    atomicAdd(&ccnt[threadIdx.x], bins[threadIdx.x]);
}

// inclusive block scan; emit per-block sums
__global__ void k_scan1(const int* __restrict__ degi, int* __restrict__ incl,
                        int* __restrict__ bsums, int n) {
  __shared__ int s[TPB];
  int i = blockIdx.x * TPB + threadIdx.x;
  int v = (i < n) ? degi[i] : 0;
  s[threadIdx.x] = v;
  __syncthreads();
#pragma unroll
  for (int off = 1; off < TPB; off <<= 1) {
    int t = (threadIdx.x >= off) ? s[threadIdx.x - off] : 0;
    __syncthreads();
    s[threadIdx.x] += t;
    __syncthreads();
  }
  if (i < n) incl[i] = s[threadIdx.x];
  if (threadIdx.x == TPB - 1) bsums[blockIdx.x] = s[TPB - 1];
}

// single-block exclusive scan of block sums (nb <= 1024)
__global__ void k_scan2(int* __restrict__ bsums, int nb) {
  __shared__ int s[1024];
  int t = threadIdx.x;
  int v = (t < nb) ? bsums[t] : 0;
  s[t] = v;
  __syncthreads();
#pragma unroll
  for (int off = 1; off < 1024; off <<= 1) {
    int u = (t >= off) ? s[t - off] : 0;
    __syncthreads();
    s[t] += u;
    __syncthreads();
  }
  if (t < nb) bsums[t] = s[t] - v;  // exclusive
}

// starts/cursor + dinv + packed meta {start, deg, dinv_bits, 0}
__global__ void k_finalize(const int* __restrict__ degi, const int* __restrict__ incl,
                           const int* __restrict__ bsums, int* __restrict__ cursor,
                           float* __restrict__ dinv, int4* __restrict__ meta, int n) {
  int i = blockIdx.x * TPB + threadIdx.x;
  if (i >= n) return;
  int dg = degi[i];
  int st = bsums[blockIdx.x] + incl[i] - dg;
  float di = rsqrtf((float)(dg + 1));  // +1 self-loop
  cursor[i] = st;
  dinv[i] = di;
  meta[i] = make_int4(st, dg, __float_as_int(di), 0);
}

// exclusive scan of 8 chunk counts -> chunk bases + tails
__global__ void k_cbase(const int* __restrict__ ccnt, int* __restrict__ cbase,
                        int* __restrict__ gtail) {
  if (threadIdx.x == 0) {
    int acc = 0;
    for (int g = 0; g < 8; ++g) {
      cbase[g] = acc;
      gtail[g] = acc;
      acc += ccnt[g];
    }
  }
}

// ---------- phase 1: bucket edges into chunk-grouped (d,s) pair arrays ----------
__global__ void k_bucket(const void* __restrict__ ei, const int* __restrict__ flag,
                         int* __restrict__ gtail, int* __restrict__ pair_d,
                         int* __restrict__ pair_s, int E, float invNc) {
  __shared__ int sd[BEB], ss[BEB];
  __shared__ int bins[8], bbase[8], cur[8];
  if (threadIdx.x < 8) bins[threadIdx.x] = 0;
  __syncthreads();
  int is64 = *flag;
  int base = blockIdx.x * BEB;
  int cnt = min(BEB, E - base);
  for (int i = threadIdx.x; i < cnt; i += TPB) {
    int e = base + i;
    int d = load_idx(ei, (long long)E + e, is64);
    int s = load_idx(ei, e, is64);
    sd[i] = d;
    ss[i] = s;
    int g = min(7, (int)((float)d * invNc));
    atomicAdd(&bins[g], 1);
  }
  __syncthreads();
  if (threadIdx.x < 8) {
    bbase[threadIdx.x] = atomicAdd(&gtail[threadIdx.x], bins[threadIdx.x]);
    cur[threadIdx.x] = 0;
  }
  __syncthreads();
  for (int i = threadIdx.x; i < cnt; i += TPB) {
    int d = sd[i];
    int s = ss[i];
    int g = min(7, (int)((float)d * invNc));
    int r = atomicAdd(&cur[g], 1);
    int pos = bbase[g] + r;
    __builtin_nontemporal_store(d, &pair_d[pos]);
    __builtin_nontemporal_store(s, &pair_s[pos]);
  }
}

// ---------- phase 2: CSR fill from chunk-grouped pairs (XCD-pinned) ----------
// blockIdx%8 = chunk g: per-XCD working set = pairs(2.4MB, nt-read) +
// CSR window(1.2MB) + cursor(0.1MB) fits one XCD's 4MB L2.
__global__ void k_scatter2(const int* __restrict__ cbase, const int* __restrict__ ccnt,
                           const int* __restrict__ pair_d, const int* __restrict__ pair_s,
                           int* __restrict__ cursor, int* __restrict__ ssrc) {
  int g = blockIdx.x & 7;
  int seg = blockIdx.x >> 3;
  int cnt = ccnt[g];
  int base = seg * SEB;
  if (base >= cnt) return;
  int lim = min(base + SEB, cnt);
  const int* pd = pair_d + cbase[g];
  const int* ps = pair_s + cbase[g];
  for (int i = base + threadIdx.x; i < lim; i += TPB) {
    int d = __builtin_nontemporal_load(&pd[i]);
    int s = __builtin_nontemporal_load(&ps[i]);
    int pos = atomicAdd(&cursor[d], 1);
    ssrc[pos] = s;
  }
}

// ---------- dense transform + prescale: msc[i,:] = (h[i,:] @ W) * dinv[i] ----------
template <int IN, int OUT>
__global__ void k_transform(const float* __restrict__ h, const float* __restrict__ W,
                            const float* __restrict__ dinv, float* __restrict__ msc,
                            int n) {
  __shared__ float sW[IN * OUT];
  for (int t = threadIdx.x; t < IN * OUT; t += blockDim.x) sW[t] = W[t];
  __syncthreads();
  int i = blockIdx.x * blockDim.x + threadIdx.x;
  if (i >= n) return;
  float xr[IN];
  const float4* hp = reinterpret_cast<const float4*>(h + (size_t)i * IN);
#pragma unroll
  for (int k4 = 0; k4 < IN / 4; ++k4) {
    float4 v = hp[k4];
    xr[k4 * 4 + 0] = v.x; xr[k4 * 4 + 1] = v.y;
    xr[k4 * 4 + 2] = v.z; xr[k4 * 4 + 3] = v.w;
  }
  float acc[OUT];
#pragma unroll
  for (int c = 0; c < OUT; ++c) acc[c] = 0.0f;
#pragma unroll
  for (int k = 0; k < IN; ++k) {
    float xv = xr[k];
#pragma unroll
    for (int c = 0; c < OUT; ++c) acc[c] = fmaf(xv, sW[k * OUT + c], acc[c]);
  }
  float di = dinv[i];
  float4* mp = reinterpret_cast<float4*>(msc + (size_t)i * OUT);
#pragma unroll
  for (int c4 = 0; c4 < OUT / 4; ++c4)
    mp[c4] = make_float4(acc[c4 * 4] * di, acc[c4 * 4 + 1] * di,
                         acc[c4 * 4 + 2] * di, acc[c4 * 4 + 3] * di);
}

// ---------- gather: 4 threads/dst, two float4 halves each, 2-edge unroll ----------
// out = dinv[d] * (msc[d] + sum_edges msc[src]) + b   (optional ReLU)
template <bool RELU>
__global__ void k_gather(const int4* __restrict__ meta, const int* __restrict__ ssrc,
                         const float* __restrict__ msc, const float* __restrict__ b,
                         float* __restrict__ outp, int n) {
  int gid = blockIdx.x * blockDim.x + threadIdx.x;
  int dst = gid >> 2;
  int q = gid & 3;
  if (dst >= n) return;
  int4 md = meta[dst];
  int s0 = md.x;
  int dg = md.y;
  float dd = __int_as_float(md.z);
  size_t o0 = (size_t)q * 4;        // first half offset within row
  size_t o1 = o0 + 16;              // second half offset
  const float* rd = msc + (size_t)dst * 32;
  float4 a0 = *reinterpret_cast<const float4*>(rd + o0);   // self-loop term
  float4 a1 = *reinterpret_cast<const float4*>(rd + o1);
  int j = 0;
  for (; j + 2 <= dg; j += 2) {
    int s1 = __builtin_nontemporal_load(&ssrc[s0 + j]);
    int s2 = __builtin_nontemporal_load(&ssrc[s0 + j + 1]);
    const float* r1 = msc + (size_t)s1 * 32;
    const float* r2 = msc + (size_t)s2 * 32;
    float4 v0 = *reinterpret_cast<const float4*>(r1 + o0);
    float4 v1 = *reinterpret_cast<const float4*>(r1 + o1);
    float4 w0 = *reinterpret_cast<const float4*>(r2 + o0);
    float4 w1 = *reinterpret_cast<const float4*>(r2 + o1);
    a0.x += v0.x + w0.x; a0.y += v0.y + w0.y; a0.z += v0.z + w0.z; a0.w += v0.w + w0.w;
    a1.x += v1.x + w1.x; a1.y += v1.y + w1.y; a1.z += v1.z + w1.z; a1.w += v1.w + w1.w;
  }
  if (j < dg) {
    int s1 = __builtin_nontemporal_load(&ssrc[s0 + j]);
    const float* r1 = msc + (size_t)s1 * 32;
    float4 v0 = *reinterpret_cast<const float4*>(r1 + o0);
    float4 v1 = *reinterpret_cast<const float4*>(r1 + o1);
    a0.x += v0.x; a0.y += v0.y; a0.z += v0.z; a0.w += v0.w;
    a1.x += v1.x; a1.y += v1.y; a1.z += v1.z; a1.w += v1.w;
  }
  float4 b0 = *reinterpret_cast<const float4*>(b + o0);
  float4 b1 = *reinterpret_cast<const float4*>(b + o1);
  a0.x = fmaf(a0.x, dd, b0.x); a0.y = fmaf(a0.y, dd, b0.y);
  a0.z = fmaf(a0.z, dd, b0.z); a0.w = fmaf(a0.w, dd, b0.w);
  a1.x = fmaf(a1.x, dd, b1.x); a1.y = fmaf(a1.y, dd, b1.y);
  a1.z = fmaf(a1.z, dd, b1.z); a1.w = fmaf(a1.w, dd, b1.w);
  if (RELU) {
    a0.x = fmaxf(a0.x, 0.0f); a0.y = fmaxf(a0.y, 0.0f);
    a0.z = fmaxf(a0.z, 0.0f); a0.w = fmaxf(a0.w, 0.0f);
    a1.x = fmaxf(a1.x, 0.0f); a1.y = fmaxf(a1.y, 0.0f);
    a1.z = fmaxf(a1.z, 0.0f); a1.w = fmaxf(a1.w, 0.0f);
  }
  float* wr = outp + (size_t)dst * 32;
  *reinterpret_cast<float4*>(wr + o0) = a0;
  *reinterpret_cast<float4*>(wr + o1) = a1;
}

extern "C" void kernel_launch(void* const* d_in, const int* in_sizes, int n_in,
                              void* d_out, int out_size, void* d_ws, size_t ws_size,
                              hipStream_t stream) {
  const float* x  = (const float*)d_in[0];
  const void*  ei = d_in[1];
  const float* W1 = (const float*)d_in[2];
  const float* b1 = (const float*)d_in[3];
  const float* W2 = (const float*)d_in[4];
  const float* b2 = (const float*)d_in[5];
  float* out = (float*)d_out;

  const int N = in_sizes[0] / 16;
  const int E = in_sizes[1] / 2;
  const int Nc = (N + 7) / 8;          // dst chunk size (locality heuristic only)
  const float invNc = 1.0f / (float)Nc;

  // workspace carve-up (256B aligned)
  char* p = (char*)d_ws;
  auto alloc = [&](size_t bytes) {
    char* r = p;
    p += (bytes + 255) & ~(size_t)255;
    return r;
  };
  int*   flag   = (int*)alloc(4);
  float* dinv   = (float*)alloc((size_t)N * 4);
  int*   degi   = (int*)alloc((size_t)N * 4);
  int*   incl   = (int*)alloc((size_t)N * 4);
  int*   cursor = (int*)alloc((size_t)N * 4);
  int4*  meta   = (int4*)alloc((size_t)N * 16);
  int*   bsums  = (int*)alloc(4096);
  int*   ccnt   = (int*)alloc(64);
  int*   cbase  = (int*)alloc(64);
  int*   gtail  = (int*)alloc(64);
  int*   ssrc   = (int*)alloc((size_t)E * 4);
  float* bufA   = (float*)alloc((size_t)N * 32 * 4);
  float* bufB   = (float*)alloc((size_t)N * 32 * 4);
  // pair staging reuses bufA/bufB: fully consumed by k_scatter2 before
  // the transforms (stream-ordered) overwrite them.
  int* pair_d = (int*)bufA;
  int* pair_s = (int*)bufB;

  const int gN  = (N + TPB - 1) / TPB;
  const int gE  = (E + TPB - 1) / TPB;
  const int gN4 = (N * 4 + TPB - 1) / TPB;
  const int gBk = (E + BEB - 1) / BEB;
  const int gS2 = ((E + SEB - 1) / SEB) * 8;

  // 0. index-width detect
  k_detect_i64<<<1, TPB, 0, stream>>>((const unsigned int*)ei, E, flag);
  // 1. degree hist + chunk counts
  k_zero<<<gN, TPB, 0, stream>>>(degi, ccnt, N);
  k_count<<<gE, TPB, 0, stream>>>(ei, flag, degi, ccnt, E, invNc);
  // 2. scans -> starts/cursor/dinv/meta, chunk bases
  k_scan1<<<gN, TPB, 0, stream>>>(degi, incl, bsums, N);
  k_scan2<<<1, 1024, 0, stream>>>(bsums, gN);
  k_finalize<<<gN, TPB, 0, stream>>>(degi, incl, bsums, cursor, dinv, meta, N);
  k_cbase<<<1, 64, 0, stream>>>(ccnt, cbase, gtail);
  // 3. bucket + CSR fill
  k_bucket<<<gBk, TPB, 0, stream>>>(ei, flag, gtail, pair_d, pair_s, E, invNc);
  k_scatter2<<<gS2, TPB, 0, stream>>>(cbase, ccnt, pair_d, pair_s, cursor, ssrc);
  // 4. layer 1
  k_transform<16, 32><<<gN, TPB, 0, stream>>>(x, W1, dinv, bufA, N);
  k_gather<true><<<gN4, TPB, 0, stream>>>(meta, ssrc, bufA, b1, bufB, N);
  // 5. layer 2
  k_transform<32, 32><<<gN, TPB, 0, stream>>>(bufB, W2, dinv, bufA, N);
  k_gather<false><<<gN4, TPB, 0, stream>>>(meta, ssrc, bufA, b2, out, N);
}